// Round 3
// baseline (717.356 us; speedup 1.0000x reference)
//
#include <hip/hip_runtime.h>
#include <hip/hip_bf16.h>
#include <math.h>

// ---------------------------------------------------------------------------
// WindowAttention (dual-lambda linear attention) for MI355X / gfx950
//   B=2048, N=64 tokens, C=384, H=12 heads, d=32
//   Fully fused kernel, 1 batch per 256-thread block, 2048 blocks.
//   LDS 73.2 KB -> 2 independent blocks per CU (two barrier domains).
//   x held in registers (xa), O intermediate never materialized: projection
//   is an incremental per-head rank-32 update into fp32 register acc_out.
// ---------------------------------------------------------------------------

typedef __attribute__((ext_vector_type(8))) short short8;   // 8 x bf16
typedef __attribute__((ext_vector_type(4))) float f32x4;
typedef __attribute__((ext_vector_type(4))) unsigned short us4;

typedef const __attribute__((address_space(1))) unsigned int gu32c;
typedef __attribute__((address_space(3))) unsigned int lu32;

#define MFMA_BF16(A,B,C) __builtin_amdgcn_mfma_f32_16x16x32_bf16(A,B,C,0,0,0)

__device__ __forceinline__ unsigned short f2bf(float f) {
  unsigned int u = __float_as_uint(f);
  u += 0x7FFFu + ((u >> 16) & 1u);            // round-to-nearest-even
  return (unsigned short)(u >> 16);
}

#define BB 2048
#define NN 64
#define CC 384
#define HH 12
#define DD 32

// workspace byte offsets (~1.2 MB)
#define WS_WT   0                         // bf16 [12][96][384] = 884736 B
#define WS_W2T  884736                    // bf16 [384][384]    = 294912 B
#define WS_WB   1179648                   // f32  [12][96]      =   4608 B
#define WS_LAM  1184256                   // f32  [12]          =     48 B

// LDS region byte offsets (total 73216 B -> 2 blocks/CU)
#define LDS_WT  0        // qkv weight dbuf: 2 x [96][64] bf16 = 24576 B
#define LDS_W2  24576    // proj head slice [384][32] bf16 (swizzled) = 24576 B
#define LDS_SK  49152    // StK [32 i][72 n] bf16 = 4608 B
#define LDS_SV  53760    // StV [32 e][72 n] bf16 = 4608 B
#define LDS_SQ  58368    // Sq  [64][56] bf16 = 7168 B
#define LDS_AT  65536    // At  [32 e][40 i] bf16 = 2560 B
#define LDS_OH  68096    // Oh  [64 n][40 e] bf16 = 5120 B
#define LDS_TOT 73216

// ---------------------------------------------------------------------------
// setup: repack qkv_w -> WT[h][c][k] (c: 0-31 q, 32-63 k, 64-95 v),
//        proj_w -> W2T[n][k], biases -> Wb[h][c], lamS[h] = 1 - lambda_full
// ---------------------------------------------------------------------------
__global__ void setup_kernel(const float* __restrict__ qkv_w,
                             const float* __restrict__ qkv_b,
                             const float* __restrict__ proj_w,
                             const float* __restrict__ lk1, const float* __restrict__ lv1,
                             const float* __restrict__ lk2, const float* __restrict__ lv2,
                             unsigned short* __restrict__ WT,
                             unsigned short* __restrict__ W2T,
                             float* __restrict__ Wb,
                             float* __restrict__ lamS)
{
  const int nWT  = HH * 96 * CC;   // 442368
  const int nW2T = CC * CC;        // 147456
  const int nWb  = HH * 96;        // 1152
  int gid = blockIdx.x * 256 + threadIdx.x;
  if (gid < nWT) {
    int h = gid / (96 * CC);
    int r = gid % (96 * CC);
    int c = r / CC;
    int k = r % CC;
    int col = (c >> 5) * CC + h * DD + (c & 31);      // q/k/v block, head, dim
    WT[gid] = f2bf(qkv_w[(size_t)k * (3 * CC) + col]);
  } else if (gid < nWT + nW2T) {
    int j = gid - nWT;
    int n = j / CC, k = j % CC;
    W2T[j] = f2bf(proj_w[(size_t)k * CC + n]);
  } else if (gid < nWT + nW2T + nWb) {
    int j = gid - nWT - nW2T;
    int h = j / 96, c = j % 96;
    Wb[j] = qkv_b[(c >> 5) * CC + h * DD + (c & 31)];
  } else if (gid < nWT + nW2T + nWb + HH) {
    int h = gid - nWT - nW2T - nWb;
    float s1 = 0.f, s2 = 0.f;
    for (int i = 0; i < DD; ++i) {
      s1 += lk1[h * DD + i] * lv1[h * DD + i];
      s2 += lk2[h * DD + i] * lv2[h * DD + i];
    }
    float lambda_init = 0.8f - 0.6f * __expf(-0.3f);
    float lam = __expf(s1) - __expf(s2) + lambda_init;
    lamS[h] = 1.0f - lam;                             // attn = (1-lambda)*A
  }
}

// ---------------------------------------------------------------------------
// fused qkv + attention + incremental projection
// grid: 2048 blocks (1 batch each), 256 threads (4 waves)
// wave roles: rg = wave>>1 (row group of 32), ch = wave&1 (col group)
// ---------------------------------------------------------------------------
__global__ __launch_bounds__(256, 2) void fused_kernel(
    const float* __restrict__ x,
    const unsigned short* __restrict__ WT,
    const float* __restrict__ Wb,
    const float* __restrict__ lamS,
    const unsigned short* __restrict__ W2T,
    const float* __restrict__ proj_b,
    float* __restrict__ out)
{
  __shared__ __align__(16) char smem[LDS_TOT];
  unsigned short* StK = (unsigned short*)(smem + LDS_SK);
  unsigned short* StV = (unsigned short*)(smem + LDS_SV);
  unsigned short* Sq  = (unsigned short*)(smem + LDS_SQ);
  unsigned short* At  = (unsigned short*)(smem + LDS_AT);
  unsigned short* Oh  = (unsigned short*)(smem + LDS_OH);
  unsigned short* W2s = (unsigned short*)(smem + LDS_W2);

  const int tid  = threadIdx.x;
  const int lane = tid & 63;
  const int wave = tid >> 6;     // 0..3
  const int quad = lane >> 4;
  const int l15  = lane & 15;
  const int rg   = wave >> 1;    // row group (32 rows)
  const int ch   = wave & 1;     // col group

  // qkv chunk staging: [96 c][64 k] = 768 x 16B slots; linear LDS dest,
  // XOR-swizzled global source (sg ^ (c&7)) -> conflict-free swizzled reads.
  auto stage_wt = [&](const unsigned short* src0, char* ldsb) {
    #pragma unroll
    for (int i = 0; i < 3; ++i) {
      int p = i * 256 + tid;
      int c = p >> 3, sg = p & 7;
      const unsigned short* sp = src0 + c * CC + ((sg ^ (c & 7)) << 3);
      __builtin_amdgcn_global_load_lds((gu32c*)(const void*)sp,
          (lu32*)(void*)(ldsb + (p & ~63) * 16), 16, 0, 0);
    }
  };
  // proj head-slice staging: [384 n][32 k] = 1536 slots, in thirds (512 slots)
  // slot swizzle sg ^ ((n>>1)&3) -> 2-way-max b128 reads.
  auto stage_w2 = [&](int h, int part) {
    #pragma unroll
    for (int i = 0; i < 2; ++i) {
      int p = part * 512 + i * 256 + tid;
      int n = p >> 2, sg = p & 3;
      const unsigned short* sp = W2T + (size_t)n * CC + h * DD
                                 + ((sg ^ ((n >> 1) & 3)) << 3);
      __builtin_amdgcn_global_load_lds((gu32c*)(const void*)sp,
          (lu32*)(void*)(smem + LDS_W2 + (p & ~63) * 16), 16, 0, 0);
    }
  };

  stage_wt(WT, smem + LDS_WT);               // head-0 chunk-0 -> buf0

  // ---- x -> registers, bf16: 32 rows/wave, 2 rows/lane, full K=384.
  //      96 VGPR, statically indexed (rule #20).
  short8 xa[2][12];
  {
    const float* xb = x + (size_t)blockIdx.x * (NN * CC);
    #pragma unroll
    for (int mt = 0; mt < 2; ++mt)
      #pragma unroll
      for (int s = 0; s < 12; ++s) {
        const float* p = xb + (rg * 32 + mt * 16 + l15) * CC + s * 32 + quad * 8;
        float4 u0 = *(const float4*)p;
        float4 u1 = *(const float4*)(p + 4);
        short8 f;
        f[0] = (short)f2bf(u0.x); f[1] = (short)f2bf(u0.y);
        f[2] = (short)f2bf(u0.z); f[3] = (short)f2bf(u0.w);
        f[4] = (short)f2bf(u1.x); f[5] = (short)f2bf(u1.y);
        f[6] = (short)f2bf(u1.z); f[7] = (short)f2bf(u1.w);
        xa[mt][s] = f;
      }
  }

  // ---- fp32 output accumulator: 32 rows x 192 cols per wave (96 VGPR) ----
  f32x4 acc_out[2][12];
  #pragma unroll
  for (int mt = 0; mt < 2; ++mt)
    #pragma unroll
    for (int t = 0; t < 12; ++t) acc_out[mt][t] = (f32x4){0.f, 0.f, 0.f, 0.f};

  __syncthreads();   // chunk-0 weights landed

  for (int h = 0; h < HH; ++h) {
    const unsigned short* Wh = WT + (size_t)h * (96 * CC);

    f32x4 acc[2][3];
    #pragma unroll
    for (int mt = 0; mt < 2; ++mt)
      #pragma unroll
      for (int t = 0; t < 3; ++t) acc[mt][t] = (f32x4){0.f, 0.f, 0.f, 0.f};

    // ---- qkv GEMM: 64 rows x 96 cols over K=384; A from registers ----
    #pragma unroll
    for (int kc = 0; kc < 6; ++kc) {
      if (kc < 5)
        stage_wt(Wh + (kc + 1) * 64, smem + LDS_WT + ((kc + 1) & 1) * 12288);
      else if (h < HH - 1)
        stage_wt(Wh + 96 * CC, smem + LDS_WT);       // next head chunk-0 -> buf0
      if (kc < 3) stage_w2(h, kc);                   // this head's W2 slice
      const unsigned short* Wt = (const unsigned short*)(smem + LDS_WT)
                                 + (kc & 1) * 6144;
      __builtin_amdgcn_s_setprio(1);
      #pragma unroll
      for (int step = 0; step < 2; ++step) {
        #pragma unroll
        for (int t = 0; t < 3; ++t) {
          const int row = ch * 48 + t * 16 + l15;
          short8 bfr = *(const short8*)(Wt + row * 64
                                        + (((step * 4 + quad) ^ (l15 & 7)) << 3));
          acc[0][t] = MFMA_BF16(xa[0][kc * 2 + step], bfr, acc[0][t]);
          acc[1][t] = MFMA_BF16(xa[1][kc * 2 + step], bfr, acc[1][t]);
        }
      }
      __builtin_amdgcn_s_setprio(0);
      __syncthreads();
    }

    // ---- epilogue: q -> Sq (*scale); fk/fv -> StK/StV transposed pack4 ----
    #pragma unroll
    for (int mt = 0; mt < 2; ++mt) {
      const int rowb = rg * 32 + mt * 16 + quad * 4;
      #pragma unroll
      for (int t = 0; t < 3; ++t) {
        const int c0 = ch * 48 + t * 16;
        const int c  = c0 + l15;
        float bias = Wb[h * 96 + c];
        if (c0 < 32) {                       // q: scale, row-major scalar
          #pragma unroll
          for (int r = 0; r < 4; ++r) {
            float v = (acc[mt][t][r] + bias) * 0.17677669529663689f;
            Sq[(rowb + r) * 56 + c] = f2bf(v);
          }
        } else {                             // k/v: ELU+1, transposed pack4
          us4 pk;
          #pragma unroll
          for (int r = 0; r < 4; ++r) {
            float v = acc[mt][t][r] + bias;
            v = (v >= 0.f) ? (v + 1.f) : __expf(v);
            pk[r] = f2bf(v);
          }
          if (c0 < 64) *(us4*)(StK + (c0 - 32 + l15) * 72 + rowb) = pk;
          else         *(us4*)(StV + (c0 - 64 + l15) * 72 + rowb) = pk;
        }
      }
    }
    __syncthreads();

    // ---- A[i][e] = sum_n fk[n][i]*fv[n][e]; At[e][i] = (1-lam)*gauss*A ----
    {
      const int i0 = (wave & 1) * 16;
      const int e0 = (wave >> 1) * 16;
      f32x4 accA = (f32x4){0.f, 0.f, 0.f, 0.f};
      #pragma unroll
      for (int n0 = 0; n0 < 64; n0 += 32) {
        short8 afr = *(const short8*)(StK + (i0 + l15) * 72 + n0 + quad * 8);
        short8 bfr = *(const short8*)(StV + (e0 + l15) * 72 + n0 + quad * 8);
        accA = MFMA_BF16(afr, bfr, accA);
      }
      const float lsc = lamS[h];
      const int e = e0 + l15;
      us4 pk;
      #pragma unroll
      for (int r = 0; r < 4; ++r) {
        int i = i0 + quad * 4 + r;
        float diff = (float)(i - e);
        pk[r] = f2bf(accA[r] * lsc * __expf(-2.0f * diff * diff)); // sigma=0.5
      }
      *(us4*)(At + e * 40 + i0 + quad * 4) = pk;     // At[e][i]
    }
    __syncthreads();

    // ---- out-tile: Oh[n][e] = q @ attn, operand-swapped MFMA so the
    //      lane holds 4 e (contiguous) x 1 n -> packed b64 Oh writes ----
    {
      short8 aq = *(const short8*)(Sq + (wave * 16 + l15) * 56 + quad * 8);
      #pragma unroll
      for (int t2 = 0; t2 < 2; ++t2) {
        short8 bA = *(const short8*)(At + (t2 * 16 + l15) * 40 + quad * 8);
        f32x4 accO = MFMA_BF16(bA, aq, ((f32x4){0.f, 0.f, 0.f, 0.f}));
        us4 pk;
        #pragma unroll
        for (int r = 0; r < 4; ++r) pk[r] = f2bf(accO[r]);
        *(us4*)(Oh + (wave * 16 + l15) * 40 + t2 * 16 + quad * 4) = pk;
      }
    }
    __syncthreads();

    // ---- incremental projection: acc_out += Oh @ W2h^T (rank-32) ----
    {
      __builtin_amdgcn_s_setprio(1);
      short8 a0 = *(const short8*)(Oh + (rg * 32 +      l15) * 40 + quad * 8);
      short8 a1 = *(const short8*)(Oh + (rg * 32 + 16 + l15) * 40 + quad * 8);
      #pragma unroll
      for (int t = 0; t < 12; ++t) {
        const int n = ch * 192 + t * 16 + l15;
        short8 b = *(const short8*)(W2s + n * 32
                                    + ((quad ^ ((n >> 1) & 3)) << 3));
        acc_out[0][t] = MFMA_BF16(a0, b, acc_out[0][t]);
        acc_out[1][t] = MFMA_BF16(a1, b, acc_out[1][t]);
      }
      __builtin_amdgcn_s_setprio(0);
    }
    __syncthreads();   // W2s/Oh handover before next head restages
  }

  // ---- tail: out = acc_out + proj_b (fp32 global write) ----
  #pragma unroll
  for (int t = 0; t < 12; ++t) {
    const int col = ch * 192 + t * 16 + l15;
    const float bias = proj_b[col];
    #pragma unroll
    for (int mt = 0; mt < 2; ++mt) {
      const size_t row0 = (size_t)blockIdx.x * NN + rg * 32 + mt * 16 + quad * 4;
      #pragma unroll
      for (int r = 0; r < 4; ++r)
        out[(row0 + r) * CC + col] = acc_out[mt][t][r] + bias;
    }
  }
}

// ---------------------------------------------------------------------------
extern "C" void kernel_launch(void* const* d_in, const int* in_sizes, int n_in,
                              void* d_out, int out_size, void* d_ws, size_t ws_size,
                              hipStream_t stream) {
  const float* x      = (const float*)d_in[0];
  const float* qkv_w  = (const float*)d_in[1];
  const float* qkv_b  = (const float*)d_in[2];
  const float* proj_w = (const float*)d_in[3];
  const float* proj_b = (const float*)d_in[4];
  const float* lk1    = (const float*)d_in[5];
  const float* lv1    = (const float*)d_in[6];
  const float* lk2    = (const float*)d_in[7];
  const float* lv2    = (const float*)d_in[8];

  char* ws = (char*)d_ws;                 // needs ~1.2 MB of workspace
  unsigned short* WT  = (unsigned short*)(ws + WS_WT);
  unsigned short* W2T = (unsigned short*)(ws + WS_W2T);
  float* Wb           = (float*)(ws + WS_WB);
  float* lamS         = (float*)(ws + WS_LAM);

  setup_kernel<<<2309, 256, 0, stream>>>(qkv_w, qkv_b, proj_w,
                                         lk1, lv1, lk2, lv2,
                                         WT, W2T, Wb, lamS);
  fused_kernel<<<2048, 256, 0, stream>>>(x, WT, Wb, lamS, W2T, proj_b,
                                         (float*)d_out);
}

// Round 4
// 585.895 us; speedup vs baseline: 1.2244x; 1.2244x over previous
//
#include <hip/hip_runtime.h>
#include <hip/hip_bf16.h>
#include <math.h>

// ---------------------------------------------------------------------------
// WindowAttention (dual-lambda linear attention) for MI355X / gfx950
//   B=2048, N=64 tokens, C=384, H=12 heads, d=32
//   Fully fused kernel, 1 batch per 256-thread block, 2048 blocks.
//   LDS 79872 B -> 2 blocks/CU = two independent barrier domains.
//   x held in registers (xa, 96 VGPR, loaded straight from global);
//   O intermediate in LDS; projection as a final LDS-sourced GEMM phase
//   (NOT register-accumulated -- round-3's version of that spilled).
// ---------------------------------------------------------------------------

typedef __attribute__((ext_vector_type(8))) short short8;   // 8 x bf16
typedef __attribute__((ext_vector_type(4))) float f32x4;
typedef __attribute__((ext_vector_type(4))) unsigned short us4;

typedef const __attribute__((address_space(1))) unsigned int gu32c;
typedef __attribute__((address_space(3))) unsigned int lu32;

#define MFMA_BF16(A,B,C) __builtin_amdgcn_mfma_f32_16x16x32_bf16(A,B,C,0,0,0)

__device__ __forceinline__ unsigned short f2bf(float f) {
  unsigned int u = __float_as_uint(f);
  u += 0x7FFFu + ((u >> 16) & 1u);            // round-to-nearest-even
  return (unsigned short)(u >> 16);
}

#define BB 2048
#define NN 64
#define CC 384
#define HH 12
#define DD 32

// workspace byte offsets (~1.2 MB)
#define WS_WT   0                         // bf16 [12][96][384] = 884736 B
#define WS_W2T  884736                    // bf16 [384][384]    = 294912 B
#define WS_WB   1179648                   // f32  [12][96]      =   4608 B
#define WS_LAM  1184256                   // f32  [12]          =     48 B

// LDS region byte offsets (total 79872 B -> 2 blocks/CU)
#define LDS_O   0        // O [64][392] bf16 = 50176 B (written per head)
#define LDS_WT  50176    // weight dbuf: 2 x 12288 B (qkv chunks / W2 chunks)
#define LDS_SK  62464    // StK [32 i][72 n] bf16 = 4608 B   (overlay WT buf1)
#define LDS_SV  67072    // StV [32 e][72 n] bf16 = 4608 B   (overlay WT buf1)
#define LDS_AT  71680    // At  [32 e][40 i] bf16 = 2560 B   (overlay WT buf1)
#define LDS_SQ  74752    // Sq  [64][40] bf16 = 5120 B
#define LDS_TOT 79872

// ---------------------------------------------------------------------------
// setup: repack qkv_w -> WT[h][c][k] (c: 0-31 q, 32-63 k, 64-95 v),
//        proj_w -> W2T[n][k], biases -> Wb[h][c], lamS[h] = 1 - lambda_full
// ---------------------------------------------------------------------------
__global__ void setup_kernel(const float* __restrict__ qkv_w,
                             const float* __restrict__ qkv_b,
                             const float* __restrict__ proj_w,
                             const float* __restrict__ lk1, const float* __restrict__ lv1,
                             const float* __restrict__ lk2, const float* __restrict__ lv2,
                             unsigned short* __restrict__ WT,
                             unsigned short* __restrict__ W2T,
                             float* __restrict__ Wb,
                             float* __restrict__ lamS)
{
  const int nWT  = HH * 96 * CC;   // 442368
  const int nW2T = CC * CC;        // 147456
  const int nWb  = HH * 96;        // 1152
  int gid = blockIdx.x * 256 + threadIdx.x;
  if (gid < nWT) {
    int h = gid / (96 * CC);
    int r = gid % (96 * CC);
    int c = r / CC;
    int k = r % CC;
    int col = (c >> 5) * CC + h * DD + (c & 31);      // q/k/v block, head, dim
    WT[gid] = f2bf(qkv_w[(size_t)k * (3 * CC) + col]);
  } else if (gid < nWT + nW2T) {
    int j = gid - nWT;
    int n = j / CC, k = j % CC;
    W2T[j] = f2bf(proj_w[(size_t)k * CC + n]);
  } else if (gid < nWT + nW2T + nWb) {
    int j = gid - nWT - nW2T;
    int h = j / 96, c = j % 96;
    Wb[j] = qkv_b[(c >> 5) * CC + h * DD + (c & 31)];
  } else if (gid < nWT + nW2T + nWb + HH) {
    int h = gid - nWT - nW2T - nWb;
    float s1 = 0.f, s2 = 0.f;
    for (int i = 0; i < DD; ++i) {
      s1 += lk1[h * DD + i] * lv1[h * DD + i];
      s2 += lk2[h * DD + i] * lv2[h * DD + i];
    }
    float lambda_init = 0.8f - 0.6f * __expf(-0.3f);
    float lam = __expf(s1) - __expf(s2) + lambda_init;
    lamS[h] = 1.0f - lam;                             // attn = (1-lambda)*A
  }
}

// ---------------------------------------------------------------------------
// fused qkv + attention + projection
// grid: 2048 blocks (1 batch each), 256 threads (4 waves)
// wave roles (qkv GEMM): rg = wave>>1 (32-row group), ch = wave&1 (48-col grp)
// ---------------------------------------------------------------------------
__global__ __launch_bounds__(256, 2) void fused_kernel(
    const float* __restrict__ x,
    const unsigned short* __restrict__ WT,
    const float* __restrict__ Wb,
    const float* __restrict__ lamS,
    const unsigned short* __restrict__ W2T,
    const float* __restrict__ proj_b,
    float* __restrict__ out)
{
  __shared__ __align__(16) char smem[LDS_TOT];
  unsigned short* Ol  = (unsigned short*)(smem + LDS_O);    // [64][392]
  unsigned short* StK = (unsigned short*)(smem + LDS_SK);
  unsigned short* StV = (unsigned short*)(smem + LDS_SV);
  unsigned short* At  = (unsigned short*)(smem + LDS_AT);
  unsigned short* Sq  = (unsigned short*)(smem + LDS_SQ);

  const int tid  = threadIdx.x;
  const int lane = tid & 63;
  const int wave = tid >> 6;     // 0..3
  const int quad = lane >> 4;
  const int l15  = lane & 15;
  const int rg   = wave >> 1;    // row group (32 rows)
  const int ch   = wave & 1;     // col group

  // qkv chunk staging: [96 c][64 k] = 768 x 16B slots; linear LDS dest,
  // XOR-swizzled global source (sg ^ (c&7)) -> <=2-way swizzled reads.
  auto stage_wt = [&](const unsigned short* src0, char* ldsb) {
    #pragma unroll
    for (int i = 0; i < 3; ++i) {
      int p = i * 256 + tid;
      int c = p >> 3, sg = p & 7;
      const unsigned short* sp = src0 + c * CC + ((sg ^ (c & 7)) << 3);
      __builtin_amdgcn_global_load_lds((gu32c*)(const void*)sp,
          (lu32*)(void*)(ldsb + (p & ~63) * 16), 16, 0, 0);
    }
  };
  // proj chunk staging: [192 n][32 k] = 768 x 16B slots (4/row);
  // slot swizzle (sg ^ ((n>>1)&3)) -> <=2-way b128 reads.
  auto stage_w2 = [&](int nh, int kc, int sel) {
    char* ldsb = smem + LDS_WT + sel * 12288;
    #pragma unroll
    for (int i = 0; i < 3; ++i) {
      int p = i * 256 + tid;
      int n = p >> 2, sg = p & 3;
      const unsigned short* sp = W2T + (size_t)(nh * 192 + n) * CC + kc * 32
                                 + ((sg ^ ((n >> 1) & 3)) << 3);
      __builtin_amdgcn_global_load_lds((gu32c*)(const void*)sp,
          (lu32*)(void*)(ldsb + (p & ~63) * 16), 16, 0, 0);
    }
  };

  stage_wt(WT, smem + LDS_WT);               // head-0 chunk-0 -> buf0

  // ---- x -> registers: 2 rows/lane x full K=384 = 96 VGPR (static idx) ----
  short8 xa[2][12];
  {
    const float* xb = x + (size_t)blockIdx.x * (NN * CC);
    #pragma unroll
    for (int mt = 0; mt < 2; ++mt)
      #pragma unroll
      for (int s = 0; s < 12; ++s) {
        const float* p = xb + (rg * 32 + mt * 16 + l15) * CC + s * 32 + quad * 8;
        float4 u0 = *(const float4*)p;
        float4 u1 = *(const float4*)(p + 4);
        short8 f;
        f[0] = (short)f2bf(u0.x); f[1] = (short)f2bf(u0.y);
        f[2] = (short)f2bf(u0.z); f[3] = (short)f2bf(u0.w);
        f[4] = (short)f2bf(u1.x); f[5] = (short)f2bf(u1.y);
        f[6] = (short)f2bf(u1.z); f[7] = (short)f2bf(u1.w);
        xa[mt][s] = f;
      }
  }
  __syncthreads();   // chunk-0 weights landed

  for (int h = 0; h < HH; ++h) {
    const unsigned short* Wh = WT + (size_t)h * (96 * CC);

    f32x4 acc[2][3];
    #pragma unroll
    for (int mt = 0; mt < 2; ++mt)
      #pragma unroll
      for (int t = 0; t < 3; ++t) acc[mt][t] = (f32x4){0.f, 0.f, 0.f, 0.f};

    // ---- qkv GEMM: 64 rows x 96 cols over K=384; A from registers ----
    #pragma unroll
    for (int kc = 0; kc < 6; ++kc) {
      if (kc < 5)
        stage_wt(Wh + (kc + 1) * 64, smem + LDS_WT + ((kc + 1) & 1) * 12288);
      else if (h < HH - 1)
        stage_wt(Wh + 96 * CC, smem + LDS_WT);       // next head chunk-0 -> buf0
      else
        stage_w2(0, 0, 0);                           // first proj chunk -> buf0
      const unsigned short* Wt = (const unsigned short*)(smem + LDS_WT)
                                 + (kc & 1) * 6144;
      __builtin_amdgcn_s_setprio(1);
      #pragma unroll
      for (int step = 0; step < 2; ++step) {
        #pragma unroll
        for (int t = 0; t < 3; ++t) {
          const int row = ch * 48 + t * 16 + l15;
          short8 bfr = *(const short8*)(Wt + row * 64
                                        + (((step * 4 + quad) ^ (l15 & 7)) << 3));
          acc[0][t] = MFMA_BF16(xa[0][kc * 2 + step], bfr, acc[0][t]);
          acc[1][t] = MFMA_BF16(xa[1][kc * 2 + step], bfr, acc[1][t]);
        }
      }
      __builtin_amdgcn_s_setprio(0);
      __syncthreads();
    }

    // ---- epilogue: q -> Sq (*scale); fk/fv -> StK/StV transposed pack4
    //      (StK/StV/At overlay WT buf1, which is dead after kc=5) ----
    #pragma unroll
    for (int mt = 0; mt < 2; ++mt) {
      const int rowb = rg * 32 + mt * 16 + quad * 4;
      #pragma unroll
      for (int t = 0; t < 3; ++t) {
        const int c0 = ch * 48 + t * 16;
        const int c  = c0 + l15;
        float bias = Wb[h * 96 + c];
        if (c0 < 32) {                       // q: scale, row-major scalar
          #pragma unroll
          for (int r = 0; r < 4; ++r) {
            float v = (acc[mt][t][r] + bias) * 0.17677669529663689f;
            Sq[(rowb + r) * 40 + c] = f2bf(v);
          }
        } else {                             // k/v: ELU+1, transposed pack4
          us4 pk;
          #pragma unroll
          for (int r = 0; r < 4; ++r) {
            float v = acc[mt][t][r] + bias;
            v = (v >= 0.f) ? (v + 1.f) : __expf(v);
            pk[r] = f2bf(v);
          }
          if (c0 < 64) *(us4*)(StK + (c0 - 32 + l15) * 72 + rowb) = pk;
          else         *(us4*)(StV + (c0 - 64 + l15) * 72 + rowb) = pk;
        }
      }
    }
    __syncthreads();

    // ---- A[i][e] = sum_n fk[n][i]*fv[n][e]; At[e][i] = (1-lam)*gauss*A ----
    {
      const int i0 = (wave & 1) * 16;
      const int e0 = (wave >> 1) * 16;
      f32x4 accA = (f32x4){0.f, 0.f, 0.f, 0.f};
      #pragma unroll
      for (int n0 = 0; n0 < 64; n0 += 32) {
        short8 afr = *(const short8*)(StK + (i0 + l15) * 72 + n0 + quad * 8);
        short8 bfr = *(const short8*)(StV + (e0 + l15) * 72 + n0 + quad * 8);
        accA = MFMA_BF16(afr, bfr, accA);
      }
      const float lsc = lamS[h];
      const int e = e0 + l15;
      us4 pk;
      #pragma unroll
      for (int r = 0; r < 4; ++r) {
        int i = i0 + quad * 4 + r;
        float diff = (float)(i - e);
        pk[r] = f2bf(accA[r] * lsc * __expf(-2.0f * diff * diff)); // sigma=0.5
      }
      *(us4*)(At + e * 40 + i0 + quad * 4) = pk;     // At[e][i]
    }
    __syncthreads();

    // ---- out-tile: operand-swapped MFMA -> lane holds 4 consecutive e;
    //      packed us4 writes into O LDS at cols h*32.. ----
    {
      short8 aq = *(const short8*)(Sq + (wave * 16 + l15) * 40 + quad * 8);
      #pragma unroll
      for (int t2 = 0; t2 < 2; ++t2) {
        short8 bA = *(const short8*)(At + (t2 * 16 + l15) * 40 + quad * 8);
        f32x4 accO = MFMA_BF16(bA, aq, ((f32x4){0.f, 0.f, 0.f, 0.f}));
        us4 pk;
        #pragma unroll
        for (int r = 0; r < 4; ++r) pk[r] = f2bf(accO[r]);
        *(us4*)(Ol + (wave * 16 + l15) * 392 + h * DD + t2 * 16 + quad * 4) = pk;
      }
    }
    __syncthreads();   // O visible; drains prefetch; frees buf1 for next head
  }

  // ---------------------------------------------------------------------
  // projection: out[64][384] = O_lds[64][384] @ W2T^T + proj_b  (fp32)
  // N in 2 halves of 192; wave tile 32 rows x 96 cols; K chunks of 32,
  // double-buffered in the WT region. xa is dead here; acc2 = 48 VGPR.
  // ---------------------------------------------------------------------
  {
    const int rg2 = wave >> 1;       // 0..1: row group (32 rows)
    const int cg2 = wave & 1;        // 0..1: col group (96 cols of the half)
    const size_t rowg0 = (size_t)blockIdx.x * NN + rg2 * 32;

    for (int nh = 0; nh < 2; ++nh) {
      f32x4 acc2[2][6];
      #pragma unroll
      for (int mt = 0; mt < 2; ++mt)
        #pragma unroll
        for (int t = 0; t < 6; ++t) acc2[mt][t] = (f32x4){0.f, 0.f, 0.f, 0.f};

      for (int kc = 0; kc < 12; ++kc) {
        if (kc < 11)      stage_w2(nh, kc + 1, (kc + 1) & 1);
        else if (nh == 0) stage_w2(1, 0, 0);
        const unsigned short* Wp = (const unsigned short*)(smem + LDS_WT)
                                   + (kc & 1) * 6144;
        __builtin_amdgcn_s_setprio(1);
        short8 a0 = *(const short8*)(Ol + (rg2 * 32 +      l15) * 392
                                     + kc * 32 + quad * 8);
        short8 a1 = *(const short8*)(Ol + (rg2 * 32 + 16 + l15) * 392
                                     + kc * 32 + quad * 8);
        #pragma unroll
        for (int t = 0; t < 6; ++t) {
          const int n = cg2 * 96 + t * 16 + l15;
          short8 b = *(const short8*)(Wp + n * 32
                                      + ((quad ^ ((n >> 1) & 3)) << 3));
          acc2[0][t] = MFMA_BF16(a0, b, acc2[0][t]);
          acc2[1][t] = MFMA_BF16(a1, b, acc2[1][t]);
        }
        __builtin_amdgcn_s_setprio(0);
        __syncthreads();
      }

      #pragma unroll
      for (int t = 0; t < 6; ++t) {
        const int col = nh * 192 + cg2 * 96 + t * 16 + l15;
        const float bias = proj_b[col];
        #pragma unroll
        for (int mt = 0; mt < 2; ++mt) {
          const size_t row0 = rowg0 + mt * 16 + quad * 4;
          #pragma unroll
          for (int r = 0; r < 4; ++r)
            out[(row0 + r) * CC + col] = acc2[mt][t][r] + bias;
        }
      }
    }
  }
}

// ---------------------------------------------------------------------------
extern "C" void kernel_launch(void* const* d_in, const int* in_sizes, int n_in,
                              void* d_out, int out_size, void* d_ws, size_t ws_size,
                              hipStream_t stream) {
  const float* x      = (const float*)d_in[0];
  const float* qkv_w  = (const float*)d_in[1];
  const float* qkv_b  = (const float*)d_in[2];
  const float* proj_w = (const float*)d_in[3];
  const float* proj_b = (const float*)d_in[4];
  const float* lk1    = (const float*)d_in[5];
  const float* lv1    = (const float*)d_in[6];
  const float* lk2    = (const float*)d_in[7];
  const float* lv2    = (const float*)d_in[8];

  char* ws = (char*)d_ws;                 // needs ~1.2 MB of workspace
  unsigned short* WT  = (unsigned short*)(ws + WS_WT);
  unsigned short* W2T = (unsigned short*)(ws + WS_W2T);
  float* Wb           = (float*)(ws + WS_WB);
  float* lamS         = (float*)(ws + WS_LAM);

  setup_kernel<<<2309, 256, 0, stream>>>(qkv_w, qkv_b, proj_w,
                                         lk1, lv1, lk2, lv2,
                                         WT, W2T, Wb, lamS);
  fused_kernel<<<2048, 256, 0, stream>>>(x, WT, Wb, lamS, W2T, proj_b,
                                         (float*)d_out);
}

// Round 5
// 548.469 us; speedup vs baseline: 1.3079x; 1.0682x over previous
//
#include <hip/hip_runtime.h>
#include <hip/hip_bf16.h>
#include <math.h>

// ---------------------------------------------------------------------------
// WindowAttention (dual-lambda linear attention) for MI355X / gfx950
//   B=2048, N=64 tokens, C=384, H=12 heads, d=32
//   Fully fused kernel, 1 batch per 256-thread block, 2048 blocks.
//   LDS 79872 B -> 2 blocks/CU. x in registers; O in LDS; final proj phase.
//   This revision: counted-vmcnt two-barrier phases (T4) -- prefetched
//   global_load_lds chunks stay in flight ACROSS barriers; attention-phase
//   barriers are lgkm-only. No full vmcnt(0) drains inside the main loop.
// ---------------------------------------------------------------------------

typedef __attribute__((ext_vector_type(8))) short short8;   // 8 x bf16
typedef __attribute__((ext_vector_type(4))) float f32x4;
typedef __attribute__((ext_vector_type(4))) unsigned short us4;

typedef const __attribute__((address_space(1))) unsigned int gu32c;
typedef __attribute__((address_space(3))) unsigned int lu32;

#define MFMA_BF16(A,B,C) __builtin_amdgcn_mfma_f32_16x16x32_bf16(A,B,C,0,0,0)

__device__ __forceinline__ unsigned short f2bf(float f) {
  unsigned int u = __float_as_uint(f);
  u += 0x7FFFu + ((u >> 16) & 1u);            // round-to-nearest-even
  return (unsigned short)(u >> 16);
}

// Barrier discipline (rule 18: asm waitcnt needs sched_barrier fences).
// BAR_VM(N): allow the N newest vmem ops to remain in flight; everything
// older (the chunk consumed this phase) must have landed. Then barrier.
#define BAR_VM(N) do {                                                     \
  asm volatile("s_waitcnt vmcnt(" #N ") lgkmcnt(0)" ::: "memory");         \
  __builtin_amdgcn_sched_barrier(0);                                       \
  __builtin_amdgcn_s_barrier();                                            \
  __builtin_amdgcn_sched_barrier(0);                                       \
} while (0)
// lgkm-only barrier: publishes LDS writes, lets vmem prefetch float across.
#define BAR_LGKM() do {                                                    \
  asm volatile("s_waitcnt lgkmcnt(0)" ::: "memory");                       \
  __builtin_amdgcn_sched_barrier(0);                                       \
  __builtin_amdgcn_s_barrier();                                            \
  __builtin_amdgcn_sched_barrier(0);                                       \
} while (0)
// plain barrier (WAR close-out: ds_reads retired before MFMA issue, so no
// waitcnt needed; asm memory fence stops IR-level motion across it).
#define BAR_PLAIN() do {                                                   \
  asm volatile("" ::: "memory");                                           \
  __builtin_amdgcn_sched_barrier(0);                                       \
  __builtin_amdgcn_s_barrier();                                            \
  __builtin_amdgcn_sched_barrier(0);                                       \
} while (0)

#define BB 2048
#define NN 64
#define CC 384
#define HH 12
#define DD 32

// workspace byte offsets (~1.2 MB)
#define WS_WT   0                         // bf16 [12][96][384] = 884736 B
#define WS_W2T  884736                    // bf16 [384][384]    = 294912 B
#define WS_WB   1179648                   // f32  [12][96]      =   4608 B
#define WS_LAM  1184256                   // f32  [12]          =     48 B

// LDS region byte offsets (total 79872 B -> 2 blocks/CU)
#define LDS_O   0        // O [64][392] bf16 = 50176 B (written per head)
#define LDS_WT  50176    // weight dbuf: 2 x 12288 B (qkv chunks / W2 chunks)
#define LDS_SK  62464    // StK [32 i][72 n] bf16 = 4608 B   (overlay WT buf1)
#define LDS_SV  67072    // StV [32 e][72 n] bf16 = 4608 B   (overlay WT buf1)
#define LDS_AT  71680    // At  [32 e][40 i] bf16 = 2560 B   (overlay WT buf1)
#define LDS_SQ  74752    // Sq  [64][40] bf16 = 5120 B
#define LDS_TOT 79872

// ---------------------------------------------------------------------------
// setup: repack qkv_w -> WT[h][c][k] (c: 0-31 q, 32-63 k, 64-95 v),
//        proj_w -> W2T[n][k], biases -> Wb[h][c], lamS[h] = 1 - lambda_full
// ---------------------------------------------------------------------------
__global__ void setup_kernel(const float* __restrict__ qkv_w,
                             const float* __restrict__ qkv_b,
                             const float* __restrict__ proj_w,
                             const float* __restrict__ lk1, const float* __restrict__ lv1,
                             const float* __restrict__ lk2, const float* __restrict__ lv2,
                             unsigned short* __restrict__ WT,
                             unsigned short* __restrict__ W2T,
                             float* __restrict__ Wb,
                             float* __restrict__ lamS)
{
  const int nWT  = HH * 96 * CC;   // 442368
  const int nW2T = CC * CC;        // 147456
  const int nWb  = HH * 96;        // 1152
  int gid = blockIdx.x * 256 + threadIdx.x;
  if (gid < nWT) {
    int h = gid / (96 * CC);
    int r = gid % (96 * CC);
    int c = r / CC;
    int k = r % CC;
    int col = (c >> 5) * CC + h * DD + (c & 31);      // q/k/v block, head, dim
    WT[gid] = f2bf(qkv_w[(size_t)k * (3 * CC) + col]);
  } else if (gid < nWT + nW2T) {
    int j = gid - nWT;
    int n = j / CC, k = j % CC;
    W2T[j] = f2bf(proj_w[(size_t)k * CC + n]);
  } else if (gid < nWT + nW2T + nWb) {
    int j = gid - nWT - nW2T;
    int h = j / 96, c = j % 96;
    Wb[j] = qkv_b[(c >> 5) * CC + h * DD + (c & 31)];
  } else if (gid < nWT + nW2T + nWb + HH) {
    int h = gid - nWT - nW2T - nWb;
    float s1 = 0.f, s2 = 0.f;
    for (int i = 0; i < DD; ++i) {
      s1 += lk1[h * DD + i] * lv1[h * DD + i];
      s2 += lk2[h * DD + i] * lv2[h * DD + i];
    }
    float lambda_init = 0.8f - 0.6f * __expf(-0.3f);
    float lam = __expf(s1) - __expf(s2) + lambda_init;
    lamS[h] = 1.0f - lam;                             // attn = (1-lambda)*A
  }
}

// ---------------------------------------------------------------------------
// fused qkv + attention + projection
// grid: 2048 blocks (1 batch each), 256 threads (4 waves)
// ---------------------------------------------------------------------------
__global__ __launch_bounds__(256, 2) void fused_kernel(
    const float* __restrict__ x,
    const unsigned short* __restrict__ WT,
    const float* __restrict__ Wb,
    const float* __restrict__ lamS,
    const unsigned short* __restrict__ W2T,
    const float* __restrict__ proj_b,
    float* __restrict__ out)
{
  __shared__ __align__(16) char smem[LDS_TOT];
  unsigned short* Ol  = (unsigned short*)(smem + LDS_O);    // [64][392]
  unsigned short* StK = (unsigned short*)(smem + LDS_SK);
  unsigned short* StV = (unsigned short*)(smem + LDS_SV);
  unsigned short* At  = (unsigned short*)(smem + LDS_AT);
  unsigned short* Sq  = (unsigned short*)(smem + LDS_SQ);

  const int tid  = threadIdx.x;
  const int lane = tid & 63;
  const int wave = tid >> 6;     // 0..3
  const int quad = lane >> 4;
  const int l15  = lane & 15;
  const int rg   = wave >> 1;    // row group (32 rows)
  const int ch   = wave & 1;     // col group

  // qkv chunk staging: [96 c][64 k] = 768 x 16B slots; linear LDS dest,
  // XOR-swizzled global source (sg ^ (c&7)). 3 vmem instrs per thread.
  auto stage_wt = [&](const unsigned short* src0, char* ldsb) {
    #pragma unroll
    for (int i = 0; i < 3; ++i) {
      int p = i * 256 + tid;
      int c = p >> 3, sg = p & 7;
      const unsigned short* sp = src0 + c * CC + ((sg ^ (c & 7)) << 3);
      __builtin_amdgcn_global_load_lds((gu32c*)(const void*)sp,
          (lu32*)(void*)(ldsb + (p & ~63) * 16), 16, 0, 0);
    }
  };
  // proj chunk staging: [192 n][32 k] = 768 x 16B slots; 3 vmem instrs.
  auto stage_w2 = [&](int nh, int kc, int sel) {
    char* ldsb = smem + LDS_WT + sel * 12288;
    #pragma unroll
    for (int i = 0; i < 3; ++i) {
      int p = i * 256 + tid;
      int n = p >> 2, sg = p & 3;
      const unsigned short* sp = W2T + (size_t)(nh * 192 + n) * CC + kc * 32
                                 + ((sg ^ ((n >> 1) & 3)) << 3);
      __builtin_amdgcn_global_load_lds((gu32c*)(const void*)sp,
          (lu32*)(void*)(ldsb + (p & ~63) * 16), 16, 0, 0);
    }
  };

  stage_wt(WT, smem + LDS_WT);               // head-0 chunk-0 -> buf0

  // ---- x -> registers: 2 rows/lane x full K=384 = 96 VGPR (static idx) ----
  short8 xa[2][12];
  {
    const float* xb = x + (size_t)blockIdx.x * (NN * CC);
    #pragma unroll
    for (int mt = 0; mt < 2; ++mt)
      #pragma unroll
      for (int s = 0; s < 12; ++s) {
        const float* p = xb + (rg * 32 + mt * 16 + l15) * CC + s * 32 + quad * 8;
        float4 u0 = *(const float4*)p;
        float4 u1 = *(const float4*)(p + 4);
        short8 f;
        f[0] = (short)f2bf(u0.x); f[1] = (short)f2bf(u0.y);
        f[2] = (short)f2bf(u0.z); f[3] = (short)f2bf(u0.w);
        f[4] = (short)f2bf(u1.x); f[5] = (short)f2bf(u1.y);
        f[6] = (short)f2bf(u1.z); f[7] = (short)f2bf(u1.w);
        xa[mt][s] = f;
      }
  }
  __syncthreads();   // full drain ONCE: x regs + chunk-0 weights landed

  for (int h = 0; h < HH; ++h) {
    const unsigned short* Wh = WT + (size_t)h * (96 * CC);

    f32x4 acc[2][3];
    #pragma unroll
    for (int mt = 0; mt < 2; ++mt)
      #pragma unroll
      for (int t = 0; t < 3; ++t) acc[mt][t] = (f32x4){0.f, 0.f, 0.f, 0.f};

    // ---- qkv GEMM: 64 rows x 96 cols over K=384; A from registers.
    //      Phase: stage k+1 | vmcnt(3)+bar (chunk k landed, k+1 in flight)
    //             | ds_read+MFMA | plain bar (WAR close-out) ----
    #pragma unroll
    for (int kc = 0; kc < 6; ++kc) {
      if (kc < 5)
        stage_wt(Wh + (kc + 1) * 64, smem + LDS_WT + ((kc + 1) & 1) * 12288);
      else if (h < HH - 1)
        stage_wt(Wh + 96 * CC, smem + LDS_WT);       // next head chunk-0 -> buf0
      else
        stage_w2(0, 0, 0);                           // first proj chunk -> buf0
      BAR_VM(3);
      const unsigned short* Wt = (const unsigned short*)(smem + LDS_WT)
                                 + (kc & 1) * 6144;
      __builtin_amdgcn_s_setprio(1);
      #pragma unroll
      for (int step = 0; step < 2; ++step) {
        #pragma unroll
        for (int t = 0; t < 3; ++t) {
          const int row = ch * 48 + t * 16 + l15;
          short8 bfr = *(const short8*)(Wt + row * 64
                                        + (((step * 4 + quad) ^ (l15 & 7)) << 3));
          acc[0][t] = MFMA_BF16(xa[0][kc * 2 + step], bfr, acc[0][t]);
          acc[1][t] = MFMA_BF16(xa[1][kc * 2 + step], bfr, acc[1][t]);
        }
      }
      __builtin_amdgcn_s_setprio(0);
      BAR_PLAIN();
    }

    // ---- epilogue: q -> Sq (*scale); fk/fv -> StK/StV transposed pack4
    //      (StK/StV/At overlay WT buf1, dead after kc=5; pending loads
    //       target buf0 only) ----
    #pragma unroll
    for (int mt = 0; mt < 2; ++mt) {
      const int rowb = rg * 32 + mt * 16 + quad * 4;
      #pragma unroll
      for (int t = 0; t < 3; ++t) {
        const int c0 = ch * 48 + t * 16;
        const int c  = c0 + l15;
        float bias = Wb[h * 96 + c];
        if (c0 < 32) {                       // q: scale, row-major scalar
          #pragma unroll
          for (int r = 0; r < 4; ++r) {
            float v = (acc[mt][t][r] + bias) * 0.17677669529663689f;
            Sq[(rowb + r) * 40 + c] = f2bf(v);
          }
        } else {                             // k/v: ELU+1, transposed pack4
          us4 pk;
          #pragma unroll
          for (int r = 0; r < 4; ++r) {
            float v = acc[mt][t][r] + bias;
            v = (v >= 0.f) ? (v + 1.f) : __expf(v);
            pk[r] = f2bf(v);
          }
          if (c0 < 64) *(us4*)(StK + (c0 - 32 + l15) * 72 + rowb) = pk;
          else         *(us4*)(StV + (c0 - 64 + l15) * 72 + rowb) = pk;
        }
      }
    }
    BAR_LGKM();

    // ---- A[i][e] = sum_n fk[n][i]*fv[n][e]; At[e][i] = (1-lam)*gauss*A ----
    {
      const int i0 = (wave & 1) * 16;
      const int e0 = (wave >> 1) * 16;
      f32x4 accA = (f32x4){0.f, 0.f, 0.f, 0.f};
      #pragma unroll
      for (int n0 = 0; n0 < 64; n0 += 32) {
        short8 afr = *(const short8*)(StK + (i0 + l15) * 72 + n0 + quad * 8);
        short8 bfr = *(const short8*)(StV + (e0 + l15) * 72 + n0 + quad * 8);
        accA = MFMA_BF16(afr, bfr, accA);
      }
      const float lsc = lamS[h];
      const int e = e0 + l15;
      us4 pk;
      #pragma unroll
      for (int r = 0; r < 4; ++r) {
        int i = i0 + quad * 4 + r;
        float diff = (float)(i - e);
        pk[r] = f2bf(accA[r] * lsc * __expf(-2.0f * diff * diff)); // sigma=0.5
      }
      *(us4*)(At + e * 40 + i0 + quad * 4) = pk;     // At[e][i]
    }
    BAR_LGKM();

    // ---- out-tile: operand-swapped MFMA -> lane holds 4 consecutive e;
    //      packed us4 writes into O LDS at cols h*32.. ----
    {
      short8 aq = *(const short8*)(Sq + (wave * 16 + l15) * 40 + quad * 8);
      #pragma unroll
      for (int t2 = 0; t2 < 2; ++t2) {
        short8 bA = *(const short8*)(At + (t2 * 16 + l15) * 40 + quad * 8);
        f32x4 accO = MFMA_BF16(bA, aq, ((f32x4){0.f, 0.f, 0.f, 0.f}));
        us4 pk;
        #pragma unroll
        for (int r = 0; r < 4; ++r) pk[r] = f2bf(accO[r]);
        *(us4*)(Ol + (wave * 16 + l15) * 392 + h * DD + t2 * 16 + quad * 4) = pk;
      }
    }
    BAR_LGKM();   // O visible; next head's kc=0 stage overwrites buf1 overlay
  }

  // ---------------------------------------------------------------------
  // projection: out[64][384] = O_lds[64][384] @ W2T^T + proj_b  (fp32)
  // Same counted-vmcnt phase discipline.
  // ---------------------------------------------------------------------
  {
    const int rg2 = wave >> 1;       // 0..1: row group (32 rows)
    const int cg2 = wave & 1;        // 0..1: col group (96 cols of the half)
    const size_t rowg0 = (size_t)blockIdx.x * NN + rg2 * 32;

    for (int nh = 0; nh < 2; ++nh) {
      f32x4 acc2[2][6];
      #pragma unroll
      for (int mt = 0; mt < 2; ++mt)
        #pragma unroll
        for (int t = 0; t < 6; ++t) acc2[mt][t] = (f32x4){0.f, 0.f, 0.f, 0.f};

      for (int kc = 0; kc < 12; ++kc) {
        int staged = 1;
        if (kc < 11)      stage_w2(nh, kc + 1, (kc + 1) & 1);
        else if (nh == 0) stage_w2(1, 0, 0);
        else              staged = 0;
        if (staged) { BAR_VM(3); } else { BAR_VM(0); }
        const unsigned short* Wp = (const unsigned short*)(smem + LDS_WT)
                                   + (kc & 1) * 6144;
        __builtin_amdgcn_s_setprio(1);
        short8 a0 = *(const short8*)(Ol + (rg2 * 32 +      l15) * 392
                                     + kc * 32 + quad * 8);
        short8 a1 = *(const short8*)(Ol + (rg2 * 32 + 16 + l15) * 392
                                     + kc * 32 + quad * 8);
        #pragma unroll
        for (int t = 0; t < 6; ++t) {
          const int n = cg2 * 96 + t * 16 + l15;
          short8 b = *(const short8*)(Wp + n * 32
                                      + ((quad ^ ((n >> 1) & 3)) << 3));
          acc2[0][t] = MFMA_BF16(a0, b, acc2[0][t]);
          acc2[1][t] = MFMA_BF16(a1, b, acc2[1][t]);
        }
        __builtin_amdgcn_s_setprio(0);
        BAR_PLAIN();
      }

      #pragma unroll
      for (int t = 0; t < 6; ++t) {
        const int col = nh * 192 + cg2 * 96 + t * 16 + l15;
        const float bias = proj_b[col];
        #pragma unroll
        for (int mt = 0; mt < 2; ++mt) {
          const size_t row0 = rowg0 + mt * 16 + quad * 4;
          #pragma unroll
          for (int r = 0; r < 4; ++r)
            out[(row0 + r) * CC + col] = acc2[mt][t][r] + bias;
        }
      }
    }
  }
}

// ---------------------------------------------------------------------------
extern "C" void kernel_launch(void* const* d_in, const int* in_sizes, int n_in,
                              void* d_out, int out_size, void* d_ws, size_t ws_size,
                              hipStream_t stream) {
  const float* x      = (const float*)d_in[0];
  const float* qkv_w  = (const float*)d_in[1];
  const float* qkv_b  = (const float*)d_in[2];
  const float* proj_w = (const float*)d_in[3];
  const float* proj_b = (const float*)d_in[4];
  const float* lk1    = (const float*)d_in[5];
  const float* lv1    = (const float*)d_in[6];
  const float* lk2    = (const float*)d_in[7];
  const float* lv2    = (const float*)d_in[8];

  char* ws = (char*)d_ws;                 // needs ~1.2 MB of workspace
  unsigned short* WT  = (unsigned short*)(ws + WS_WT);
  unsigned short* W2T = (unsigned short*)(ws + WS_W2T);
  float* Wb           = (float*)(ws + WS_WB);
  float* lamS         = (float*)(ws + WS_LAM);

  setup_kernel<<<2309, 256, 0, stream>>>(qkv_w, qkv_b, proj_w,
                                         lk1, lv1, lk2, lv2,
                                         WT, W2T, Wb, lamS);
  fused_kernel<<<2048, 256, 0, stream>>>(x, WT, Wb, lamS, W2T, proj_b,
                                         (float*)d_out);
}